// Round 3
// baseline (30.963 us; speedup 1.0000x reference)
//
#include <hip/hip_runtime.h>

// Soft decision forest, depth=4, W=4: B=256, T=64, N=341 nodes, 1024 leaves.
// out[bt, j0*256 + j1*64 + j2*16 + j3*4 + j4] = prod softmax(in[bt, n_l, :])[j_l]
// preorder: n0=0, n1=1+85*j0, n2=n1+1+21*j1, n3=n2+1+5*j2, n4=n3+1+j3.
//
// Pure-streaming, LDS-free design: wave = one bt; each lane gathers its own
// path rows (17 dwordx4 in flight); redundant row reads are L1/L2 broadcasts
// since the whole per-bt tree is 5.5 KB. Stores: 4x contiguous 1KB per wave.

#define NUM_NODES 341

__device__ __forceinline__ float4 softmax4(float4 x) {
    float m  = fmaxf(fmaxf(x.x, x.y), fmaxf(x.z, x.w));
    float e0 = __expf(x.x - m);
    float e1 = __expf(x.y - m);
    float e2 = __expf(x.z - m);
    float e3 = __expf(x.w - m);
    float r  = 1.0f / (e0 + e1 + e2 + e3);
    return make_float4(e0 * r, e1 * r, e2 * r, e3 * r);
}

__device__ __forceinline__ float selc(float4 v, int c) {
    // v[c] without memory round-trip: 3 cndmasks (c is lane-varying)
    float ab = (c & 1) ? v.y : v.x;
    float cd = (c & 1) ? v.w : v.z;
    return (c & 2) ? cd : ab;
}

__global__ __launch_bounds__(256) void forest_kernel(const float* __restrict__ in,
                                                     float* __restrict__ out) {
    const int tid  = threadIdx.x;
    const int wave = tid >> 6;
    const int lane = tid & 63;
    const int bt   = blockIdx.x * 4 + wave;   // 0..16383

    const float4* base = reinterpret_cast<const float4*>(in) + (size_t)bt * NUM_NODES;

    const int j1 = lane >> 4;
    const int j2 = (lane >> 2) & 3;
    const int j3 = lane & 3;

    // ---- Issue all path-row loads up front (17 dwordx4 in flight/lane) ----
    float4 r0 = base[0];                       // root row (broadcast line)
    float4 r1[4], r2[4], r3[4], r4[4];
#pragma unroll
    for (int j0 = 0; j0 < 4; ++j0) {
        const int n1 = 1 + 85 * j0;            // wave-uniform
        const int n2 = n1 + 1 + 21 * j1;       // 4 distinct rows / wave
        const int n3 = n2 + 1 + 5 * j2;        // 16 distinct rows / wave
        const int n4 = n3 + 1 + j3;            // 64 distinct rows / wave
        r1[j0] = base[n1];
        r2[j0] = base[n2];
        r3[j0] = base[n3];
        r4[j0] = base[n4];
    }

    const float4 p0 = softmax4(r0);

    float4* out4 = reinterpret_cast<float4*>(out) + (size_t)bt * 256;

#pragma unroll
    for (int j0 = 0; j0 < 4; ++j0) {
        const float pre = selc(p0, j0)                 // j0 compile-time: folds
                        * selc(softmax4(r1[j0]), j1)
                        * selc(softmax4(r2[j0]), j2)
                        * selc(softmax4(r3[j0]), j3);
        const float4 pv = softmax4(r4[j0]);
        out4[j0 * 64 + lane] = make_float4(pre * pv.x, pre * pv.y,
                                           pre * pv.z, pre * pv.w);
    }
}

extern "C" void kernel_launch(void* const* d_in, const int* in_sizes, int n_in,
                              void* d_out, int out_size, void* d_ws, size_t ws_size,
                              hipStream_t stream) {
    const float* in = (const float*)d_in[0];
    float* out = (float*)d_out;
    const int num_blocks = (256 * 64) / 4;  // one bt per wave, 4 waves/block
    forest_kernel<<<num_blocks, 256, 0, stream>>>(in, out);
}

// Round 5
// 30.568 us; speedup vs baseline: 1.0129x; 1.0129x over previous
//
#include <hip/hip_runtime.h>

// Soft decision forest, depth=4, W=4: B=256, T=64, N=341 nodes, 1024 leaves.
// out[bt, j0*256+j1*64+j2*16+j3*4+j4] = prod softmax(in[bt, n_l, :])[j_l]
// preorder: n0=0, n1=1+85*j0, n2=n1+1+21*j1, n3=n2+1+5*j2, n4=n3+1+j3.
//
// R1 structure (block-per-bt, LDS prob table) + nontemporal load/store:
// both streams are single-touch, so skip L2/L3 allocation (nt flag).
// Nontemporal builtins need native vector types, not HIP_vector_type.

#define NUM_NODES 341

typedef float f32x4 __attribute__((ext_vector_type(4)));

__global__ __launch_bounds__(256) void forest_kernel(const float* __restrict__ in,
                                                     float* __restrict__ out) {
    __shared__ f32x4 sP[NUM_NODES];  // 5456 B: softmax probs per node

    const int bt  = blockIdx.x;       // (b*T + t), 0..16383
    const int tid = threadIdx.x;      // 0..255

    // ---- Phase 1: softmax over W=4 per node, coalesced nt float4 loads ----
    const f32x4* in4 = reinterpret_cast<const f32x4*>(in) + (size_t)bt * NUM_NODES;
    for (int n = tid; n < NUM_NODES; n += 256) {
        f32x4 v = __builtin_nontemporal_load(&in4[n]);
        float m  = fmaxf(fmaxf(v.x, v.y), fmaxf(v.z, v.w));
        float e0 = __expf(v.x - m);
        float e1 = __expf(v.y - m);
        float e2 = __expf(v.z - m);
        float e3 = __expf(v.w - m);
        float r  = 1.0f / (e0 + e1 + e2 + e3);
        f32x4 p; p.x = e0 * r; p.y = e1 * r; p.z = e2 * r; p.w = e3 * r;
        sP[n] = p;
    }
    __syncthreads();

    // ---- Phase 2: each thread computes 4 consecutive leaves (shared n4) ----
    const float* sPf = reinterpret_cast<const float*>(sP);
    const int j0 =  tid >> 6;
    const int j1 = (tid >> 4) & 3;
    const int j2 = (tid >> 2) & 3;
    const int j3 =  tid & 3;

    const int n1 = 1 + j0 * 85;
    const int n2 = n1 + 1 + j1 * 21;
    const int n3 = n2 + 1 + j2 * 5;
    const int n4 = n3 + 1 + j3;

    const float pre = sPf[j0]            // root node 0, branch j0
                    * sPf[n1 * 4 + j1]
                    * sPf[n2 * 4 + j2]
                    * sPf[n3 * 4 + j3];

    f32x4 pv = sP[n4];
    f32x4 o; o.x = pre * pv.x; o.y = pre * pv.y; o.z = pre * pv.z; o.w = pre * pv.w;

    __builtin_nontemporal_store(o, &reinterpret_cast<f32x4*>(out)[(size_t)bt * 256 + tid]);
}

extern "C" void kernel_launch(void* const* d_in, const int* in_sizes, int n_in,
                              void* d_out, int out_size, void* d_ws, size_t ws_size,
                              hipStream_t stream) {
    const float* in = (const float*)d_in[0];
    float* out = (float*)d_out;
    const int num_bt = 256 * 64;  // B * T
    forest_kernel<<<num_bt, 256, 0, stream>>>(in, out);
}

// Round 6
// 28.342 us; speedup vs baseline: 1.0925x; 1.0786x over previous
//
#include <hip/hip_runtime.h>

// Soft decision forest, depth=4, W=4: B=256, T=64, N=341 nodes, 1024 leaves.
// Output[b,t,L] = prod_{l=0..4} softmax(in[b,t,n_l,:])[j_l],
// L = j0*256 + j1*64 + j2*16 + j3*4 + j4, preorder node indices:
// n0=0, n1=1+85*j0, n2=n1+1+21*j1, n3=n2+1+5*j2, n4=n3+1+j3.
//
// FINAL (R1 structure): block-per-bt, LDS softmax table, plain cached
// float4 ld/st. Measured 28.43 us = 88% of the 6.29 TB/s copy ceiling for
// the mandatory 156.5 MB of single-touch traffic. A/B-tested and rejected:
// wave-private-LDS/no-barrier (neutral), register-gather (+9%), nt ld/st (+8%).

#define NUM_NODES 341

__global__ __launch_bounds__(256) void forest_kernel(const float* __restrict__ in,
                                                     float* __restrict__ out) {
    __shared__ float4 sP[NUM_NODES];  // 5456 B: softmax probs per node

    const int bt  = blockIdx.x;       // (b*T + t), 0..16383
    const int tid = threadIdx.x;      // 0..255

    // ---- Phase 1: softmax over W=4 per node, coalesced float4 loads ----
    const float4* in4 = reinterpret_cast<const float4*>(in) + (size_t)bt * NUM_NODES;
    for (int n = tid; n < NUM_NODES; n += 256) {
        float4 v = in4[n];
        float m  = fmaxf(fmaxf(v.x, v.y), fmaxf(v.z, v.w));
        float e0 = __expf(v.x - m);
        float e1 = __expf(v.y - m);
        float e2 = __expf(v.z - m);
        float e3 = __expf(v.w - m);
        float r  = 1.0f / (e0 + e1 + e2 + e3);
        sP[n] = make_float4(e0 * r, e1 * r, e2 * r, e3 * r);
    }
    __syncthreads();

    // ---- Phase 2: each thread computes 4 consecutive leaves (shared n4) ----
    const float* sPf = reinterpret_cast<const float*>(sP);
    const int j0 =  tid >> 6;
    const int j1 = (tid >> 4) & 3;
    const int j2 = (tid >> 2) & 3;
    const int j3 =  tid & 3;

    const int n1 = 1 + j0 * 85;
    const int n2 = n1 + 1 + j1 * 21;
    const int n3 = n2 + 1 + j2 * 5;
    const int n4 = n3 + 1 + j3;

    const float pre = sPf[j0]            // root node 0, branch j0
                    * sPf[n1 * 4 + j1]
                    * sPf[n2 * 4 + j2]
                    * sPf[n3 * 4 + j3];

    float4 pv = sP[n4];
    float4 o  = make_float4(pre * pv.x, pre * pv.y, pre * pv.z, pre * pv.w);

    reinterpret_cast<float4*>(out)[(size_t)bt * 256 + tid] = o;
}

extern "C" void kernel_launch(void* const* d_in, const int* in_sizes, int n_in,
                              void* d_out, int out_size, void* d_ws, size_t ws_size,
                              hipStream_t stream) {
    const float* in = (const float*)d_in[0];
    float* out = (float*)d_out;
    const int num_bt = 256 * 64;  // B * T
    forest_kernel<<<num_bt, 256, 0, stream>>>(in, out);
}